// Round 1
// baseline (528.261 us; speedup 1.0000x reference)
//
#include <hip/hip_runtime.h>
#include <math.h>

#define NG 32
#define NK 1024
#define ND 64
#define NB 4096

// ws layout (floats): [0 .. NG*NK) c2 | [NG*NK .. NG*NK+NK) counts(int) | [NG*NK+NK] loss sum

__global__ void vq_init(int* __restrict__ counts, float* __restrict__ losssum) {
    int i = blockIdx.x * blockDim.x + threadIdx.x;
    if (i < NK) counts[i] = 0;
    if (i == 0) *losssum = 0.f;
}

__global__ void vq_c2(const float* __restrict__ cb, float* __restrict__ c2) {
    int i = blockIdx.x * blockDim.x + threadIdx.x;
    if (i >= NG * NK) return;
    const float* c = cb + (size_t)i * ND;
    float s0 = 0.f, s1 = 0.f, s2 = 0.f, s3 = 0.f;
#pragma unroll
    for (int d = 0; d < ND; d += 4) {
        float4 v = *reinterpret_cast<const float4*>(c + d);
        s0 = fmaf(v.x, v.x, s0);
        s1 = fmaf(v.y, v.y, s1);
        s2 = fmaf(v.z, v.z, s2);
        s3 = fmaf(v.w, v.w, s3);
    }
    c2[i] = (s0 + s1) + (s2 + s3);
}

// One wave = 64 batch rows of one group g (lane = row). Codebook access is
// wave-uniform -> scalar loads; argmin is purely per-lane.
__global__ __launch_bounds__(256) void vq_main(
        const float* __restrict__ z, const float* __restrict__ cb,
        const float* __restrict__ c2, float* __restrict__ qout,
        float* __restrict__ idxout, int* __restrict__ counts,
        float* __restrict__ losssum) {
    const int tid = threadIdx.x;
    const int g = blockIdx.x & (NG - 1);
    const int rowblk = blockIdx.x >> 5;
    const int row = rowblk * 256 + tid;

    // Load this lane's 64-dim z slice into registers.
    const float* zrow = z + (size_t)row * (NG * ND) + (size_t)g * ND;
    float zv[ND];
#pragma unroll
    for (int i = 0; i < ND / 4; i++) {
        float4 v = reinterpret_cast<const float4*>(zrow)[i];
        zv[4 * i + 0] = v.x; zv[4 * i + 1] = v.y;
        zv[4 * i + 2] = v.z; zv[4 * i + 3] = v.w;
    }
    float t0 = 0.f, t1 = 0.f, t2 = 0.f, t3 = 0.f;
#pragma unroll
    for (int d = 0; d < ND; d += 4) {
        t0 = fmaf(zv[d + 0], zv[d + 0], t0);
        t1 = fmaf(zv[d + 1], zv[d + 1], t1);
        t2 = fmaf(zv[d + 2], zv[d + 2], t2);
        t3 = fmaf(zv[d + 3], zv[d + 3], t3);
    }
    const float z2 = (t0 + t1) + (t2 + t3);

    const float* cg = cb + (size_t)g * NK * ND;
    const float* c2g = c2 + (size_t)g * NK;

    float best = 3.402823466e38f;
    int bestk = 0;
#pragma unroll 1
    for (int k = 0; k < NK; k++) {
        const float* ck = cg + (size_t)k * ND;  // wave-uniform address
        float a0 = 0.f, a1 = 0.f, a2 = 0.f, a3 = 0.f;
#pragma unroll
        for (int d = 0; d < ND; d += 4) {
            a0 = fmaf(zv[d + 0], ck[d + 0], a0);
            a1 = fmaf(zv[d + 1], ck[d + 1], a1);
            a2 = fmaf(zv[d + 2], ck[d + 2], a2);
            a3 = fmaf(zv[d + 3], ck[d + 3], a3);
        }
        float zc = (a0 + a1) + (a2 + a3);
        float dist = (z2 - 2.0f * zc) + c2g[k];
        if (dist < best) { best = dist; bestk = k; }  // strict < == first-min ties
    }

    // Epilogue: gather winning code, write z + (zq - z) (reference's exact fp ops),
    // accumulate (z - zq)^2.
    const float* cbest = cg + (size_t)bestk * ND;  // divergent per lane
    float* qrow = qout + (size_t)row * (NG * ND) + (size_t)g * ND;
    float l0 = 0.f, l1 = 0.f, l2 = 0.f, l3 = 0.f;
#pragma unroll
    for (int i = 0; i < ND / 4; i++) {
        float4 c = reinterpret_cast<const float4*>(cbest)[i];
        float zx = zv[4 * i + 0], zy = zv[4 * i + 1];
        float zz = zv[4 * i + 2], zw = zv[4 * i + 3];
        float4 st;
        st.x = zx + (c.x - zx);
        st.y = zy + (c.y - zy);
        st.z = zz + (c.z - zz);
        st.w = zw + (c.w - zw);
        reinterpret_cast<float4*>(qrow)[i] = st;
        float dx = zx - c.x, dy = zy - c.y, dz = zz - c.z, dw = zw - c.w;
        l0 = fmaf(dx, dx, l0); l1 = fmaf(dy, dy, l1);
        l2 = fmaf(dz, dz, l2); l3 = fmaf(dw, dw, l3);
    }
    float lsum = (l0 + l1) + (l2 + l3);

    idxout[(size_t)row * NG + g] = (float)bestk;
    atomicAdd(&counts[bestk], 1);

#pragma unroll
    for (int off = 32; off > 0; off >>= 1) lsum += __shfl_down(lsum, off, 64);
    if ((tid & 63) == 0) atomicAdd(losssum, lsum);
}

__global__ void vq_final(const int* __restrict__ counts,
                         const float* __restrict__ losssum,
                         float* __restrict__ out) {
    __shared__ float red[256];
    int tid = threadIdx.x;
    float e = 0.f;
    for (int k = tid; k < NK; k += 256) {
        float u = (float)counts[k] * (1.0f / 131072.0f);
        e -= u * logf(u + 1e-10f);
    }
    red[tid] = e;
    __syncthreads();
    for (int s = 128; s > 0; s >>= 1) {
        if (tid < s) red[tid] += red[tid + s];
        __syncthreads();
    }
    if (tid == 0) {
        float loss = *losssum * (1.0f / 8388608.0f);
        float ent = red[0];
        out[0] = loss;      // commitment_loss
        out[1] = loss;      // codebook_loss (forward-identical)
        out[2] = ent;       // entropy
        out[3] = expf(ent); // perplexity
    }
}

extern "C" void kernel_launch(void* const* d_in, const int* in_sizes, int n_in,
                              void* d_out, int out_size, void* d_ws, size_t ws_size,
                              hipStream_t stream) {
    const float* z = (const float*)d_in[0];
    const float* cb = (const float*)d_in[1];
    float* out = (float*)d_out;
    float* qout = out;                                  // 8388608
    float* idxout = out + (size_t)NB * NG * ND;         // +131072
    float* scal = idxout + (size_t)NB * NG;             // 4 scalars

    float* c2 = (float*)d_ws;
    int* counts = (int*)(c2 + NG * NK);
    float* losssum = (float*)(counts + NK);

    vq_init<<<(NK + 255) / 256, 256, 0, stream>>>(counts, losssum);
    vq_c2<<<(NG * NK + 255) / 256, 256, 0, stream>>>(cb, c2);
    vq_main<<<NG * (NB / 256), 256, 0, stream>>>(z, cb, c2, qout, idxout, counts, losssum);
    vq_final<<<1, 256, 0, stream>>>(counts, losssum, scal);
}

// Round 3
// 502.502 us; speedup vs baseline: 1.0513x; 1.0513x over previous
//
#include <hip/hip_runtime.h>
#include <math.h>

#define NG 32
#define NK 1024
#define ND 64
#define NB 4096
#define KSPLIT 4
#define KCHUNK (NK / KSPLIT)

// ws layout (floats): [0 .. NG*NK) c2 | counts(int)[NK] | loss sum

__global__ void vq_init(int* __restrict__ counts, float* __restrict__ losssum) {
    int i = blockIdx.x * blockDim.x + threadIdx.x;
    if (i < NK) counts[i] = 0;
    if (i == 0) *losssum = 0.f;
}

__global__ void vq_c2(const float* __restrict__ cb, float* __restrict__ c2) {
    int i = blockIdx.x * blockDim.x + threadIdx.x;
    if (i >= NG * NK) return;
    const float* c = cb + (size_t)i * ND;
    float s0 = 0.f, s1 = 0.f, s2 = 0.f, s3 = 0.f;
#pragma unroll
    for (int d = 0; d < ND; d += 4) {
        float4 v = *reinterpret_cast<const float4*>(c + d);
        s0 = fmaf(v.x, v.x, s0);
        s1 = fmaf(v.y, v.y, s1);
        s2 = fmaf(v.z, v.z, s2);
        s3 = fmaf(v.w, v.w, s3);
    }
    c2[i] = (s0 + s1) + (s2 + s3);
}

// Epilogue d-slice for wave W (compile-time so zv[] indexing stays in registers).
template <int W>
__device__ __forceinline__ float epi_slice(const float* __restrict__ cbest,
                                           float* __restrict__ qrow,
                                           const float (&zv)[ND]) {
    float l0 = 0.f, l1 = 0.f, l2 = 0.f, l3 = 0.f;
#pragma unroll
    for (int i = 0; i < 4; i++) {
        float4 c = reinterpret_cast<const float4*>(cbest)[W * 4 + i];
        float zx = zv[W * 16 + 4 * i + 0], zy = zv[W * 16 + 4 * i + 1];
        float zz = zv[W * 16 + 4 * i + 2], zw = zv[W * 16 + 4 * i + 3];
        float4 st;
        st.x = zx + (c.x - zx);
        st.y = zy + (c.y - zy);
        st.z = zz + (c.z - zz);
        st.w = zw + (c.w - zw);
        reinterpret_cast<float4*>(qrow)[W * 4 + i] = st;
        float dx = zx - c.x, dy = zy - c.y, dz = zz - c.z, dw = zw - c.w;
        l0 = fmaf(dx, dx, l0); l1 = fmaf(dy, dy, l1);
        l2 = fmaf(dz, dz, l2); l3 = fmaf(dw, dw, l3);
    }
    return (l0 + l1) + (l2 + l3);
}

// Block = 4 waves over the same 64 batch rows of one group; wave w scans
// codewords [w*256, (w+1)*256). Lane = row. Codebook access is wave-uniform
// (forced via readfirstlane) -> s_load; argmin combine across waves via LDS.
__global__ __launch_bounds__(256) void vq_main(
        const float* __restrict__ z, const float* __restrict__ cb,
        const float* __restrict__ c2, float* __restrict__ qout,
        float* __restrict__ idxout, int* __restrict__ counts,
        float* __restrict__ losssum) {
    const int tid = threadIdx.x;
    const int lane = tid & 63;
    const int wu = __builtin_amdgcn_readfirstlane(tid >> 6);  // wave id, uniform
    const int g = blockIdx.x & (NG - 1);
    const int rowblk = blockIdx.x >> 5;          // 0..63
    const int row = rowblk * 64 + lane;

    const float* zrow = z + (size_t)row * (NG * ND) + (size_t)g * ND;
    float zv[ND];
#pragma unroll
    for (int i = 0; i < ND / 4; i++) {
        float4 v = reinterpret_cast<const float4*>(zrow)[i];
        zv[4 * i + 0] = v.x; zv[4 * i + 1] = v.y;
        zv[4 * i + 2] = v.z; zv[4 * i + 3] = v.w;
    }
    float t0 = 0.f, t1 = 0.f, t2 = 0.f, t3 = 0.f;
#pragma unroll
    for (int d = 0; d < ND; d += 4) {
        t0 = fmaf(zv[d + 0], zv[d + 0], t0);
        t1 = fmaf(zv[d + 1], zv[d + 1], t1);
        t2 = fmaf(zv[d + 2], zv[d + 2], t2);
        t3 = fmaf(zv[d + 3], zv[d + 3], t3);
    }
    const float z2 = (t0 + t1) + (t2 + t3);

    const float* cg = cb + (size_t)g * NK * ND;
    const float* c2g = c2 + (size_t)g * NK;
    const int k0 = wu * KCHUNK;                  // uniform (SGPR)

    float best = 3.402823466e38f;
    int bestk = k0;
#pragma unroll 1
    for (int k = k0; k < k0 + KCHUNK; k++) {
        const float* ck = cg + (size_t)k * ND;   // wave-uniform -> s_load
        float a0 = 0.f, a1 = 0.f, a2 = 0.f, a3 = 0.f;
#pragma unroll
        for (int d = 0; d < ND; d += 4) {
            a0 = fmaf(zv[d + 0], ck[d + 0], a0);
            a1 = fmaf(zv[d + 1], ck[d + 1], a1);
            a2 = fmaf(zv[d + 2], ck[d + 2], a2);
            a3 = fmaf(zv[d + 3], ck[d + 3], a3);
        }
        float zc = (a0 + a1) + (a2 + a3);
        float dist = (z2 - 2.0f * zc) + c2g[k];
        if (dist < best) { best = dist; bestk = k; }  // strict < == first-min ties
    }

    // Combine per-lane argmin across the 4 k-ranges (fold in wave order).
    __shared__ float s_best[KSPLIT][64];
    __shared__ int s_bk[KSPLIT][64];
    __shared__ int s_win[64];
    s_best[wu][lane] = best;
    s_bk[wu][lane] = bestk;
    __syncthreads();
    if (wu == 0) {
        float b = s_best[0][lane];
        int bk = s_bk[0][lane];
#pragma unroll
        for (int q = 1; q < KSPLIT; q++) {
            float d = s_best[q][lane];
            int kk = s_bk[q][lane];
            if (d < b) { b = d; bk = kk; }
        }
        s_win[lane] = bk;
        idxout[(size_t)row * NG + g] = (float)bk;
        atomicAdd(&counts[bk], 1);
    }
    __syncthreads();

    const int bk = s_win[lane];
    const float* cbest = cg + (size_t)bk * ND;   // divergent per lane
    float* qrow = qout + (size_t)row * (NG * ND) + (size_t)g * ND;
    float lsum;
    switch (wu) {
        case 0: lsum = epi_slice<0>(cbest, qrow, zv); break;
        case 1: lsum = epi_slice<1>(cbest, qrow, zv); break;
        case 2: lsum = epi_slice<2>(cbest, qrow, zv); break;
        default: lsum = epi_slice<3>(cbest, qrow, zv); break;
    }
#pragma unroll
    for (int off = 32; off > 0; off >>= 1) lsum += __shfl_down(lsum, off, 64);
    if (lane == 0) atomicAdd(losssum, lsum);
}

__global__ void vq_final(const int* __restrict__ counts,
                         const float* __restrict__ losssum,
                         float* __restrict__ out) {
    __shared__ float red[256];
    int tid = threadIdx.x;
    float e = 0.f;
    for (int k = tid; k < NK; k += 256) {
        float u = (float)counts[k] * (1.0f / 131072.0f);
        e -= u * logf(u + 1e-10f);
    }
    red[tid] = e;
    __syncthreads();
    for (int s = 128; s > 0; s >>= 1) {
        if (tid < s) red[tid] += red[tid + s];
        __syncthreads();
    }
    if (tid == 0) {
        float loss = *losssum * (1.0f / 8388608.0f);
        float ent = red[0];
        out[0] = loss;      // commitment_loss
        out[1] = loss;      // codebook_loss (forward-identical)
        out[2] = ent;       // entropy
        out[3] = expf(ent); // perplexity
    }
}

extern "C" void kernel_launch(void* const* d_in, const int* in_sizes, int n_in,
                              void* d_out, int out_size, void* d_ws, size_t ws_size,
                              hipStream_t stream) {
    const float* z = (const float*)d_in[0];
    const float* cb = (const float*)d_in[1];
    float* out = (float*)d_out;
    float* qout = out;                                  // 8388608
    float* idxout = out + (size_t)NB * NG * ND;         // +131072
    float* scal = idxout + (size_t)NB * NG;             // 4 scalars

    float* c2 = (float*)d_ws;
    int* counts = (int*)(c2 + NG * NK);
    float* losssum = (float*)(counts + NK);

    vq_init<<<(NK + 255) / 256, 256, 0, stream>>>(counts, losssum);
    vq_c2<<<(NG * NK + 255) / 256, 256, 0, stream>>>(cb, c2);
    vq_main<<<(NB / 64) * NG, 256, 0, stream>>>(z, cb, c2, qout, idxout, counts, losssum);
    vq_final<<<1, 256, 0, stream>>>(counts, losssum, scal);
}